// Round 9
// baseline (63.958 us; speedup 1.0000x reference)
//
#include <hip/hip_runtime.h>
#include <hip/hip_bf16.h>

#define B_   4
#define Hf   128
#define Wf   128
#define HC   32
#define WC   32
#define SR   15
#define PAD  7
#define FR   125
#define FRP  139      // padded pooled grid: 125 + 14

typedef float vfloat4 __attribute__((ext_vector_type(4)));

static __device__ __forceinline__ unsigned short f2bf(float x) {
    __hip_bfloat16 h = __float2bfloat16(x);
    unsigned short u; __builtin_memcpy(&u, &h, 2); return u;
}

static __device__ __forceinline__ float mrg(float x, float y, bool hi, int m) {
    float u0 = hi ? x : y;
    float t  = __shfl_xor(u0, m, 64);
    return (hi ? y : x) + t;
}

// ---- fused pooling ----
__global__ __launch_bounds__(256) void pool_fused(const float* __restrict__ in0,
                                                  const float* __restrict__ in1,
                                                  float* __restrict__ fc,
                                                  unsigned short* __restrict__ fr16) {
    int bid = blockIdx.x;
    if (bid < 4 * 18 * 18) {
        int yt = bid % 18;
        int xt = (bid / 18) % 18;
        int b  = bid / (18 * 18);
        int c4 = threadIdx.x & 31;
        int x  = xt * 8 + (threadIdx.x >> 5);    // padded x, 0..143
        if (x >= FRP) return;
        int y0 = yt * 8;
        bool xin = (x >= PAD) && (x < PAD + FR);

        float4 h[11];
        if (xin) {
            int xi = x - PAD;
            const float4* base = reinterpret_cast<const float4*>(in1) + (size_t)(b * Hf * Wf) * 32 + c4;
#pragma unroll
            for (int k = 0; k < 11; ++k) {
                int r = y0 - PAD + k;
                r = r < 0 ? 0 : (r > Hf - 1 ? Hf - 1 : r);
                float4 s = make_float4(0.f, 0.f, 0.f, 0.f);
#pragma unroll
                for (int dx = 0; dx < 4; ++dx) {
                    float4 v = base[(size_t)(r * Wf + xi + dx) * 32];
                    s.x += v.x; s.y += v.y; s.z += v.z; s.w += v.w;
                }
                h[k] = s;
            }
        }
        const float s = 1.0f / 16.0f;
        ushort4* fr4 = reinterpret_cast<ushort4*>(fr16);
#pragma unroll
        for (int yy = 0; yy < 8; ++yy) {
            int y = y0 + yy;
            if (y >= FRP) continue;
            ushort4 o = make_ushort4(0, 0, 0, 0);
            if (xin && y >= PAD && y < PAD + FR) {
                o.x = f2bf((h[yy].x + h[yy+1].x + h[yy+2].x + h[yy+3].x) * s);
                o.y = f2bf((h[yy].y + h[yy+1].y + h[yy+2].y + h[yy+3].y) * s);
                o.z = f2bf((h[yy].z + h[yy+1].z + h[yy+2].z + h[yy+3].z) * s);
                o.w = f2bf((h[yy].w + h[yy+1].w + h[yy+2].w + h[yy+3].w) * s);
            }
            fr4[((size_t)(b * FRP + y) * FRP + x) * 32 + c4] = o;
        }
    } else {
        int t = (bid - 4 * 18 * 18) * 256 + threadIdx.x;   // 512 blocks
        int c4 = t & 31;
        int j  = (t >> 5) & 31;
        int i  = (t >> 10) & 31;
        int b  = t >> 15;
        const float4* in = reinterpret_cast<const float4*>(in0);
        size_t base = ((size_t)(b * Hf + 4 * i) * Wf + 4 * j) * 32 + c4;
        float4 acc = make_float4(0.f, 0.f, 0.f, 0.f);
#pragma unroll
        for (int dy = 0; dy < 4; ++dy)
#pragma unroll
            for (int dx = 0; dx < 4; ++dx) {
                float4 v = in[base + dy * (Wf * 32) + dx * 32];
                acc.x += v.x; acc.y += v.y; acc.z += v.z; acc.w += v.w;
            }
        const float sc = 1.0f / 16.0f;
        acc.x *= sc; acc.y *= sc; acc.z *= sc; acc.w *= sc;
        reinterpret_cast<float4*>(fc)[t] = acc;
    }
}

// ---- correlation + leaky_relu + 4x4 replicate (R6 version, known-good) ----
__global__ __launch_bounds__(256) void corr_kernel(const float* __restrict__ fc,
                                                   const unsigned short* __restrict__ fr16,
                                                   float* __restrict__ out) {
    int blk  = blockIdx.x;
    int cell = (blk & 7) * 512 + (blk >> 3);         // XCD swizzle (4096 % 8 == 0)
    int j = cell & 31;
    int i = (cell >> 5) & 31;
    int b = cell >> 10;

    int tid = threadIdx.x;
    int g   = tid >> 5;
    int gl  = tid & 31;

    __shared__ float corr_rep[900];

    float4 f = reinterpret_cast<const float4*>(fc)[((b * HC + i) * WC + j) * 32 + gl];

    const uint2* frbase = reinterpret_cast<const uint2*>(fr16);
    bool h16 = gl & 16, h8 = gl & 8, h4 = gl & 4, h2 = gl & 2;
    int vidx = ((gl >> 4) & 1) * 8 + ((gl >> 3) & 1) * 4 + ((gl >> 2) & 1) * 2 + ((gl >> 1) & 1);

#pragma unroll
    for (int pass = 0; pass < 2; ++pass) {
        int u = g + pass * 8;
        if (u < SR) {
            int row = 4 * i + u;                     // padded coords, always in-bounds
            const uint2* p = frbase + ((size_t)(b * FRP + row) * FRP + 4 * j) * 32 + gl;

            float a[16];
#pragma unroll
            for (int k = 0; k < 16; ++k) a[k] = 0.f;
#pragma unroll
            for (int v = 0; v < SR; ++v) {
                uint2 w = p[v * 32];
                float r0 = __uint_as_float(w.x << 16);
                float r1 = __uint_as_float(w.x & 0xffff0000u);
                float r2 = __uint_as_float(w.y << 16);
                float r3 = __uint_as_float(w.y & 0xffff0000u);
                a[v] = fmaf(f.x, r0, fmaf(f.y, r1, fmaf(f.z, r2, f.w * r3)));
            }

            float bb[8], cc[4], dd[2], e;
#pragma unroll
            for (int k = 0; k < 8; ++k) bb[k] = mrg(a[k], a[k + 8], h16, 16);
#pragma unroll
            for (int k = 0; k < 4; ++k) cc[k] = mrg(bb[k], bb[k + 4], h8, 8);
#pragma unroll
            for (int k = 0; k < 2; ++k) dd[k] = mrg(cc[k], cc[k + 2], h4, 4);
            e = mrg(dd[0], dd[1], h2, 2);
            e += __shfl_xor(e, 1, 64);

            if (vidx < SR) {
                float cv = e * (1.0f / 128.0f);
                float val = cv > 0.f ? cv : 0.1f * cv;
                int uvq = u * SR + vidx;
                int c0 = (gl & 1) * 225;
                corr_rep[c0 + uvq] = val;
                corr_rep[c0 + 450 + uvq] = val;
            }
        }
    }
    __syncthreads();

    if (tid < SR * SR) {
        vfloat4 val = *reinterpret_cast<const vfloat4*>(&corr_rep[4 * tid]);
        vfloat4* out4 = reinterpret_cast<vfloat4*>(out);
        long pix   = (long)(b * Hf + 4 * i) * Wf + 4 * j;
        long base4 = pix * (SR * SR) / 4;
#pragma unroll
        for (int di = 0; di < 4; ++di)
            __builtin_nontemporal_store(val, &out4[base4 + di * (Wf * SR * SR / 4) + tid]);
    }
}

extern "C" void kernel_launch(void* const* d_in, const int* in_sizes, int n_in,
                              void* d_out, int out_size, void* d_ws, size_t ws_size,
                              hipStream_t stream) {
    const float* f0 = (const float*)d_in[0];
    const float* f1 = (const float*)d_in[1];
    float* out = (float*)d_out;

    float* fc = (float*)d_ws;                                        // 2 MB fp32
    unsigned short* fr16 = (unsigned short*)(fc + B_ * HC * WC * 128);  // 19.8 MB bf16, padded

    pool_fused<<<4 * 18 * 18 + 512, 256, 0, stream>>>(f0, f1, fc, fr16);
    // MEASUREMENT: corr launched twice (idempotent — writes identical data).
    // total = pool + 2*corr  =>  corr = total - 45.3us baseline.
    corr_kernel<<<B_ * HC * WC, 256, 0, stream>>>(fc, fr16, out);
    corr_kernel<<<B_ * HC * WC, 256, 0, stream>>>(fc, fr16, out);
}

// Round 10
// 46.739 us; speedup vs baseline: 1.3684x; 1.3684x over previous
//
#include <hip/hip_runtime.h>
#include <hip/hip_bf16.h>

#define B_   4
#define Hf   128
#define Wf   128
#define HC   32
#define WC   32
#define SR   15
#define PAD  7
#define FR   125
#define FRP  139      // padded pooled grid: 125 + 14

typedef float vfloat4 __attribute__((ext_vector_type(4)));
typedef _Float16 half2v __attribute__((ext_vector_type(2)));

static __device__ __forceinline__ unsigned short f2h(float x) {
    _Float16 h = (_Float16)x;
    unsigned short u; __builtin_memcpy(&u, &h, 2); return u;
}

static __device__ __forceinline__ float mrg(float x, float y, bool hi, int m) {
    float u0 = hi ? x : y;
    float t  = __shfl_xor(u0, m, 64);
    return (hi ? y : x) + t;
}

// ---- kernel 1: f_c = avg_pool(in0, 4, stride 4) -> (4,32,32,128) fp32 ----
__global__ __launch_bounds__(256) void pool_fc(const float* __restrict__ in0,
                                               float* __restrict__ fc) {
    int t = blockIdx.x * 256 + threadIdx.x;          // 131072 float4
    int c4 = t & 31;
    int j  = (t >> 5) & 31;
    int i  = (t >> 10) & 31;
    int b  = t >> 15;
    const float4* in = reinterpret_cast<const float4*>(in0);
    size_t base = ((size_t)(b * Hf + 4 * i) * Wf + 4 * j) * 32 + c4;
    float4 acc = make_float4(0.f, 0.f, 0.f, 0.f);
#pragma unroll
    for (int dy = 0; dy < 4; ++dy)
#pragma unroll
        for (int dx = 0; dx < 4; ++dx) {
            float4 v = in[base + dy * (Wf * 32) + dx * 32];
            acc.x += v.x; acc.y += v.y; acc.z += v.z; acc.w += v.w;
        }
    const float s = 1.0f / 16.0f;
    acc.x *= s; acc.y *= s; acc.z *= s; acc.w *= s;
    reinterpret_cast<float4*>(fc)[t] = acc;
}

// ---- kernel 2: f_r_pad = pad(avg_pool(in1,4,1),7) -> (4,139,139,128) fp16 ----
__global__ __launch_bounds__(256) void pool_fr(const float* __restrict__ in1,
                                               unsigned short* __restrict__ fr16) {
    int bid = blockIdx.x;
    int yt = bid % 18;
    int xt = (bid / 18) % 18;
    int b  = bid / (18 * 18);
    int c4 = threadIdx.x & 31;
    int x  = xt * 8 + (threadIdx.x >> 5);    // padded x, 0..143
    if (x >= FRP) return;
    int y0 = yt * 8;
    bool xin = (x >= PAD) && (x < PAD + FR);

    float4 h[11];
    if (xin) {
        int xi = x - PAD;
        const float4* base = reinterpret_cast<const float4*>(in1) + (size_t)(b * Hf * Wf) * 32 + c4;
#pragma unroll
        for (int k = 0; k < 11; ++k) {
            int r = y0 - PAD + k;
            r = r < 0 ? 0 : (r > Hf - 1 ? Hf - 1 : r);
            float4 s = make_float4(0.f, 0.f, 0.f, 0.f);
#pragma unroll
            for (int dx = 0; dx < 4; ++dx) {
                float4 v = base[(size_t)(r * Wf + xi + dx) * 32];
                s.x += v.x; s.y += v.y; s.z += v.z; s.w += v.w;
            }
            h[k] = s;
        }
    }
    const float s = 1.0f / 16.0f;
    ushort4* fr4 = reinterpret_cast<ushort4*>(fr16);
#pragma unroll
    for (int yy = 0; yy < 8; ++yy) {
        int y = y0 + yy;
        if (y >= FRP) continue;
        ushort4 o = make_ushort4(0, 0, 0, 0);
        if (xin && y >= PAD && y < PAD + FR) {
            o.x = f2h((h[yy].x + h[yy+1].x + h[yy+2].x + h[yy+3].x) * s);
            o.y = f2h((h[yy].y + h[yy+1].y + h[yy+2].y + h[yy+3].y) * s);
            o.z = f2h((h[yy].z + h[yy+1].z + h[yy+2].z + h[yy+3].z) * s);
            o.w = f2h((h[yy].w + h[yy+1].w + h[yy+2].w + h[yy+3].w) * s);
        }
        fr4[((size_t)(b * FRP + y) * FRP + x) * 32 + c4] = o;
    }
}

// ---- correlation + leaky_relu + 4x4 replicate ----
// block per cell; 8 groups x 32 lanes; group g owns u = g, g+8; lane = 4 channels
// inner loop: 1 uint2 load + 2 v_dot2_f32_f16 per v
__global__ __launch_bounds__(256) void corr_kernel(const float* __restrict__ fc,
                                                   const unsigned short* __restrict__ fr16,
                                                   float* __restrict__ out) {
    int blk  = blockIdx.x;
    int cell = (blk & 7) * 512 + (blk >> 3);         // XCD swizzle (4096 % 8 == 0)
    int j = cell & 31;
    int i = (cell >> 5) & 31;
    int b = cell >> 10;

    int tid = threadIdx.x;
    int g   = tid >> 5;
    int gl  = tid & 31;

    __shared__ float corr_rep[900];

    // my 4 channels of f_c as two half2 pairs
    float4 f = reinterpret_cast<const float4*>(fc)[((b * HC + i) * WC + j) * 32 + gl];
    half2v f01 = { (_Float16)f.x, (_Float16)f.y };
    half2v f23 = { (_Float16)f.z, (_Float16)f.w };

    const uint2* frbase = reinterpret_cast<const uint2*>(fr16);
    bool h16 = gl & 16, h8 = gl & 8, h4 = gl & 4, h2 = gl & 2;
    int vidx = ((gl >> 4) & 1) * 8 + ((gl >> 3) & 1) * 4 + ((gl >> 2) & 1) * 2 + ((gl >> 1) & 1);

#pragma unroll
    for (int pass = 0; pass < 2; ++pass) {
        int u = g + pass * 8;
        if (u < SR) {
            int row = 4 * i + u;                     // padded coords, always in-bounds
            const uint2* p = frbase + ((size_t)(b * FRP + row) * FRP + 4 * j) * 32 + gl;

            float a[16];
            a[15] = 0.f;
#pragma unroll
            for (int v = 0; v < SR; ++v) {
                uint2 w = p[v * 32];
                half2v w01 = __builtin_bit_cast(half2v, w.x);
                half2v w23 = __builtin_bit_cast(half2v, w.y);
                float d = __builtin_amdgcn_fdot2(w01, f01, 0.0f, false);
                a[v] = __builtin_amdgcn_fdot2(w23, f23, d, false);
            }

            float bb[8], cc[4], dd[2], e;
#pragma unroll
            for (int k = 0; k < 8; ++k) bb[k] = mrg(a[k], a[k + 8], h16, 16);
#pragma unroll
            for (int k = 0; k < 4; ++k) cc[k] = mrg(bb[k], bb[k + 4], h8, 8);
#pragma unroll
            for (int k = 0; k < 2; ++k) dd[k] = mrg(cc[k], cc[k + 2], h4, 4);
            e = mrg(dd[0], dd[1], h2, 2);
            e += __shfl_xor(e, 1, 64);

            if (vidx < SR) {
                float cv = e * (1.0f / 128.0f);
                float val = cv > 0.f ? cv : 0.1f * cv;
                int uvq = u * SR + vidx;
                int c0 = (gl & 1) * 225;
                corr_rep[c0 + uvq] = val;
                corr_rep[c0 + 450 + uvq] = val;
            }
        }
    }
    __syncthreads();

    if (tid < SR * SR) {
        vfloat4 val = *reinterpret_cast<const vfloat4*>(&corr_rep[4 * tid]);
        vfloat4* out4 = reinterpret_cast<vfloat4*>(out);
        long pix   = (long)(b * Hf + 4 * i) * Wf + 4 * j;
        long base4 = pix * (SR * SR) / 4;
#pragma unroll
        for (int di = 0; di < 4; ++di)
            __builtin_nontemporal_store(val, &out4[base4 + di * (Wf * SR * SR / 4) + tid]);
    }
}

extern "C" void kernel_launch(void* const* d_in, const int* in_sizes, int n_in,
                              void* d_out, int out_size, void* d_ws, size_t ws_size,
                              hipStream_t stream) {
    const float* f0 = (const float*)d_in[0];
    const float* f1 = (const float*)d_in[1];
    float* out = (float*)d_out;

    float* fc = (float*)d_ws;                                        // 2 MB fp32
    unsigned short* fr16 = (unsigned short*)(fc + B_ * HC * WC * 128);  // 19.8 MB fp16, padded

    pool_fc<<<512, 256, 0, stream>>>(f0, fc);
    pool_fr<<<4 * 18 * 18, 256, 0, stream>>>(f1, fr16);
    corr_kernel<<<B_ * HC * WC, 256, 0, stream>>>(fc, fr16, out);
}

// Round 12
// 45.079 us; speedup vs baseline: 1.4188x; 1.0368x over previous
//
#include <hip/hip_runtime.h>

#define B_   4
#define Hf   128
#define Wf   128
#define HC   32
#define WC   32
#define SR   15
#define PAD  7
#define FR   125
#define PH   142   // padded in1h rows (max index 4*31+17 = 141)
#define PW   144   // padded in1h width (18 strips * 8)

typedef float vfloat4 __attribute__((ext_vector_type(4)));
typedef _Float16 half2v __attribute__((ext_vector_type(2)));

static __device__ __forceinline__ unsigned short f2h(float x) {
    _Float16 h = (_Float16)x;
    unsigned short u; __builtin_memcpy(&u, &h, 2); return u;
}

static __device__ __forceinline__ float mrg(float x, float y, bool hi, int m) {
    float u0 = hi ? x : y;
    float t  = __shfl_xor(u0, m, 64);
    return (hi ? y : x) + t;
}

// ---- prep kernel ----
// blocks [0,1296): in1h = zero-pad(fp16(in1), 7) -> (4,142,144,128), 1 load + 1 store per elem
// blocks [1296,1808): f_c = avg_pool(in0,4,4) -> (4,32,32,128) fp32
__global__ __launch_bounds__(256) void poolcvt(const float* __restrict__ in0,
                                               const float* __restrict__ in1,
                                               float* __restrict__ fc,
                                               unsigned short* __restrict__ in1h) {
    int bid = blockIdx.x;
    if (bid < 4 * 18 * 18) {
        int yt = bid % 18;
        int xt = (bid / 18) % 18;
        int b  = bid / 324;
        int c4 = threadIdx.x & 31;
        int x  = xt * 8 + (threadIdx.x >> 5);    // 0..143, all stored
        bool xin = (x >= PAD) && (x < PAD + Wf);
        const float4* src = reinterpret_cast<const float4*>(in1) + (size_t)(b * Hf * Wf) * 32 + c4;
        ushort4* dst = reinterpret_cast<ushort4*>(in1h);
#pragma unroll
        for (int yy = 0; yy < 8; ++yy) {
            int y = yt * 8 + yy;
            if (y >= PH) continue;
            ushort4 o = make_ushort4(0, 0, 0, 0);
            if (xin && y >= PAD && y < PAD + Hf) {
                float4 v = src[(size_t)((y - PAD) * Wf + (x - PAD)) * 32];
                o.x = f2h(v.x); o.y = f2h(v.y); o.z = f2h(v.z); o.w = f2h(v.w);
            }
            dst[((size_t)(b * PH + y) * PW + x) * 32 + c4] = o;
        }
    } else {
        int t = (bid - 4 * 18 * 18) * 256 + threadIdx.x;   // 512 blocks
        int c4 = t & 31;
        int j  = (t >> 5) & 31;
        int i  = (t >> 10) & 31;
        int b  = t >> 15;
        const float4* in = reinterpret_cast<const float4*>(in0);
        size_t base = ((size_t)(b * Hf + 4 * i) * Wf + 4 * j) * 32 + c4;
        float4 acc = make_float4(0.f, 0.f, 0.f, 0.f);
#pragma unroll
        for (int dy = 0; dy < 4; ++dy)
#pragma unroll
            for (int dx = 0; dx < 4; ++dx) {
                float4 v = in[base + dy * (Wf * 32) + dx * 32];
                acc.x += v.x; acc.y += v.y; acc.z += v.z; acc.w += v.w;
            }
        const float sc = 1.0f / 16.0f;
        acc.x *= sc; acc.y *= sc; acc.z *= sc; acc.w *= sc;
        reinterpret_cast<float4*>(fc)[t] = acc;
    }
}

// ---- g-space correlation ----
// per cell: g[t][s] = dot_C(fc, in1h[4i+t][4j+s]) for 18x18 window (raw pixels),
// then corr(u,v) = boxfilter4x4(g)/2048, masked to 0 outside valid fr range, leaky, replicate.
__global__ __launch_bounds__(256) void corr_g(const float* __restrict__ fc,
                                              const unsigned short* __restrict__ in1h,
                                              float* __restrict__ out) {
    int blk  = blockIdx.x;
    int cell = (blk & 7) * 512 + (blk >> 3);     // XCD swizzle: slab/XCD = 78 rows x 144 = 2.9 MB
    int j = cell & 31;
    int i = (cell >> 5) & 31;
    int b = cell >> 10;

    int tid = threadIdx.x;
    int g   = tid >> 5;                          // 8 groups
    int gl  = tid & 31;                          // lane = 4 channels

    __shared__ float g_s[18][20];
    __shared__ float h_s[18][16];
    __shared__ float rep[900];

    // fc slice -> fp16 pairs
    float4 f = reinterpret_cast<const float4*>(fc)[((b * HC + i) * WC + j) * 32 + gl];
    half2v f01 = { (_Float16)f.x, (_Float16)f.y };
    half2v f23 = { (_Float16)f.z, (_Float16)f.w };

    const uint2* base = reinterpret_cast<const uint2*>(in1h)
                        + ((size_t)(b * PH + 4 * i) * PW + 4 * j) * 32 + gl;

    bool h16 = gl & 16, h8 = gl & 8, h4 = gl & 4, h2 = gl & 2;
    int vidx = ((gl >> 4) & 1) * 8 + ((gl >> 3) & 1) * 4 + ((gl >> 2) & 1) * 2 + ((gl >> 1) & 1);

    int nrows = (g < 2) ? 3 : 2;                 // rows g, g+8, (g+16 for g<2) => 18 rows
    for (int rr = 0; rr < nrows; ++rr) {
        int row = g + rr * 8;
        const uint2* p = base + (size_t)row * (PW * 32);

        float a[18];
#pragma unroll
        for (int s = 0; s < 18; ++s) {
            uint2 w = p[s * 32];
            half2v w01 = __builtin_bit_cast(half2v, w.x);
            half2v w23 = __builtin_bit_cast(half2v, w.y);
            float d = __builtin_amdgcn_fdot2(w01, f01, 0.0f, false);
            a[s] = __builtin_amdgcn_fdot2(w23, f23, d, false);
        }

        // batched tree for cols 0..15 (R6-verified)
        float bb[8], cc[4], dd[2], e;
#pragma unroll
        for (int k = 0; k < 8; ++k) bb[k] = mrg(a[k], a[k + 8], h16, 16);
#pragma unroll
        for (int k = 0; k < 4; ++k) cc[k] = mrg(bb[k], bb[k + 4], h8, 8);
#pragma unroll
        for (int k = 0; k < 2; ++k) dd[k] = mrg(cc[k], cc[k + 2], h4, 4);
        e = mrg(dd[0], dd[1], h2, 2);
        e += __shfl_xor(e, 1, 64);
        if (!(gl & 1)) g_s[row][vidx] = e;

        // cols 16,17: plain butterfly (stays within the 32-lane group)
        float e16 = a[16], e17 = a[17];
#pragma unroll
        for (int m = 1; m <= 16; m <<= 1) {
            e16 += __shfl_xor(e16, m, 64);
            e17 += __shfl_xor(e17, m, 64);
        }
        if (gl == 0) { g_s[row][16] = e16; g_s[row][17] = e17; }
    }
    __syncthreads();

    // separable 4x4 box: horizontal (270 items > 256 threads -> strided loop; R11 bug fixed)
    for (int q = tid; q < 18 * 15; q += 256) {
        int y = q / 15, v = q % 15;
        h_s[y][v] = g_s[y][v] + g_s[y][v + 1] + g_s[y][v + 2] + g_s[y][v + 3];
    }
    __syncthreads();

    // vertical + scale + mask + leaky + replicate
    if (tid < 225) {
        int u = tid / 15, v = tid % 15;
        float s4 = h_s[u][v] + h_s[u + 1][v] + h_s[u + 2][v] + h_s[u + 3][v];
        int r = 4 * i + u - PAD, c = 4 * j + v - PAD;
        bool ok = (r >= 0) && (r < FR) && (c >= 0) && (c < FR);
        float cv = s4 * (1.0f / 2048.0f);
        float val = ok ? (cv > 0.f ? cv : 0.1f * cv) : 0.f;
        rep[tid] = val; rep[225 + tid] = val; rep[450 + tid] = val; rep[675 + tid] = val;
    }
    __syncthreads();

    if (tid < 225) {
        vfloat4 val = *reinterpret_cast<const vfloat4*>(&rep[4 * tid]);
        vfloat4* out4 = reinterpret_cast<vfloat4*>(out);
        long pix   = (long)(b * Hf + 4 * i) * Wf + 4 * j;
        long base4 = pix * (SR * SR) / 4;
#pragma unroll
        for (int di = 0; di < 4; ++di)
            __builtin_nontemporal_store(val, &out4[base4 + di * (Wf * SR * SR / 4) + tid]);
    }
}

extern "C" void kernel_launch(void* const* d_in, const int* in_sizes, int n_in,
                              void* d_out, int out_size, void* d_ws, size_t ws_size,
                              hipStream_t stream) {
    const float* f0 = (const float*)d_in[0];
    const float* f1 = (const float*)d_in[1];
    float* out = (float*)d_out;

    float* fc = (float*)d_ws;                                        // 2 MB fp32
    unsigned short* in1h = (unsigned short*)(fc + B_ * HC * WC * 128);  // 21 MB fp16, padded

    poolcvt<<<4 * 18 * 18 + 512, 256, 0, stream>>>(f0, f1, fc, in1h);
    corr_g<<<B_ * HC * WC, 256, 0, stream>>>(fc, in1h, out);
}